// Round 1
// baseline (3069.684 us; speedup 1.0000x reference)
//
#include <hip/hip_runtime.h>

#define NN 50000
#define NE 800000
// channels: 128 in/hid, 64 lat (x2 heads)

// ---------------- norm kernels ----------------
__global__ __launch_bounds__(256) void k_init_deg(float* deg) {
    int i = blockIdx.x * 256 + threadIdx.x;
    if (i < NN) deg[i] = 1.0f;   // self-loop
}

__global__ __launch_bounds__(256) void k_count(const int* __restrict__ dst, float* __restrict__ deg) {
    int e = blockIdx.x * 256 + threadIdx.x;
    if (e < NE) atomicAdd(&deg[dst[e]], 1.0f);
}

__global__ __launch_bounds__(256) void k_dinv(float* deg) {
    int i = blockIdx.x * 256 + threadIdx.x;
    if (i < NN) deg[i] = rsqrtf(deg[i]);
}

__global__ __launch_bounds__(256) void k_enorm(const int* __restrict__ src, const int* __restrict__ dst,
                                               const float* __restrict__ dinv, float* __restrict__ en) {
    int e = blockIdx.x * 256 + threadIdx.x;
    if (e < NE) en[e] = dinv[src[e]] * dinv[dst[e]];
}

// ---------------- dense GEMM: C[N,128] = X[N,128] @ W[128,128] ----------------
// block = 256 threads, 32 rows per block. W fully in LDS (64KB), X tile 16KB.
__global__ __launch_bounds__(256) void k_gemm(const float* __restrict__ X, const float* __restrict__ W,
                                              float* __restrict__ C, int N) {
    __shared__ float Ws[128 * 128];
    __shared__ float Xs[32 * 128];
    int tid  = threadIdx.x;
    int row0 = blockIdx.x * 32;

    const float4* W4 = (const float4*)W;
    float4* Ws4 = (float4*)Ws;
    for (int i = tid; i < 128 * 32; i += 256) Ws4[i] = W4[i];

    const float4* X4 = (const float4*)X;
    float4* Xs4 = (float4*)Xs;
    for (int i = tid; i < 32 * 32; i += 256) {
        int r = i >> 5, kk = i & 31;
        int gr = row0 + r;
        Xs4[i] = (gr < N) ? X4[gr * 32 + kk] : make_float4(0.f, 0.f, 0.f, 0.f);
    }
    __syncthreads();

    int c  = tid & 127;
    int rr = tid >> 7;   // 0 or 1
    float acc[16];
#pragma unroll
    for (int j = 0; j < 16; ++j) acc[j] = 0.f;

    for (int k = 0; k < 128; ++k) {
        float w = Ws[k * 128 + c];
#pragma unroll
        for (int j = 0; j < 16; ++j) acc[j] += Xs[(rr + 2 * j) * 128 + k] * w;
    }

#pragma unroll
    for (int j = 0; j < 16; ++j) {
        int r = row0 + rr + 2 * j;
        if (r < N) C[r * 128 + c] = acc[j];
    }
}

// ---------------- edge scatter: agg[dst] += h[src] * en ----------------
// one thread per (edge, 4 channels): 25.6M threads, float4 gather + 4 atomics
__global__ __launch_bounds__(256) void k_scatter(const float* __restrict__ h, const float* __restrict__ en,
                                                 const int* __restrict__ src, const int* __restrict__ dst,
                                                 float* __restrict__ agg) {
    int i = blockIdx.x * 256 + threadIdx.x;
    if (i >= NE * 32) return;
    int e = i >> 5, q = i & 31;
    float s = en[e];
    const float4* h4 = (const float4*)h;
    float4 v = h4[src[e] * 32 + q];
    float* a = &agg[dst[e] * 128 + q * 4];
    atomicAdd(a + 0, v.x * s);
    atomicAdd(a + 1, v.y * s);
    atomicAdd(a + 2, v.z * s);
    atomicAdd(a + 3, v.w * s);
}

// ---------------- self-loop + bias + relu ----------------
// out = relu(agg + h*dinv^2 + b); out may alias agg or h (same-index rw) -> no restrict
__global__ __launch_bounds__(256) void k_fuse(const float* agg, const float* hin,
                                              const float* __restrict__ dinv, const float* __restrict__ b,
                                              float* out) {
    int i = blockIdx.x * 256 + threadIdx.x;
    if (i >= NN * 32) return;
    int n = i >> 5, q = i & 31;
    float sn = dinv[n]; sn *= sn;
    const float4* a4 = (const float4*)agg;
    const float4* h4 = (const float4*)hin;
    const float4* b4 = (const float4*)b;
    float4 a = a4[i], h = h4[i], bb = b4[q];
    float4 r;
    r.x = fmaxf(a.x + h.x * sn + bb.x, 0.f);
    r.y = fmaxf(a.y + h.y * sn + bb.y, 0.f);
    r.z = fmaxf(a.z + h.z * sn + bb.z, 0.f);
    r.w = fmaxf(a.w + h.w * sn + bb.w, 0.f);
    ((float4*)out)[i] = r;
}

// ---------------- final: mu = X@Wmu+bmu, lv = X@Wlv+blv, packed output ----------------
__global__ __launch_bounds__(256) void k_final(const float* __restrict__ X,
                                               const float4* __restrict__ Wmu4, const float* __restrict__ bmu,
                                               const float4* __restrict__ Wlv4, const float* __restrict__ blv,
                                               float* __restrict__ out, int N) {
    __shared__ float Ws[128 * 128];
    __shared__ float Xs[32 * 128];
    __shared__ float Bs[128];
    int tid  = threadIdx.x;
    int row0 = blockIdx.x * 32;

    float4* Ws4 = (float4*)Ws;
    for (int i = tid; i < 2048; i += 256) {
        int k = i >> 4, c4 = i & 15;
        Ws4[k * 32 + c4]      = Wmu4[i];   // cols 0..63 = mu
        Ws4[k * 32 + 16 + c4] = Wlv4[i];   // cols 64..127 = lv
    }
    if (tid < 64) { Bs[tid] = bmu[tid]; Bs[64 + tid] = blv[tid]; }

    const float4* X4 = (const float4*)X;
    float4* Xs4 = (float4*)Xs;
    for (int i = tid; i < 32 * 32; i += 256) {
        int r = i >> 5, kk = i & 31;
        int gr = row0 + r;
        Xs4[i] = (gr < N) ? X4[gr * 32 + kk] : make_float4(0.f, 0.f, 0.f, 0.f);
    }
    __syncthreads();

    int c  = tid & 127;
    int rr = tid >> 7;
    float acc[16];
#pragma unroll
    for (int j = 0; j < 16; ++j) acc[j] = 0.f;

    for (int k = 0; k < 128; ++k) {
        float w = Ws[k * 128 + c];
#pragma unroll
        for (int j = 0; j < 16; ++j) acc[j] += Xs[(rr + 2 * j) * 128 + k] * w;
    }

    float bias = Bs[c];
#pragma unroll
    for (int j = 0; j < 16; ++j) {
        int r = row0 + rr + 2 * j;
        if (r < N) {
            if (c < 64) out[r * 64 + c] = acc[j] + bias;
            else        out[NN * 64 + r * 64 + (c - 64)] = acc[j] + bias;
        }
    }
}

extern "C" void kernel_launch(void* const* d_in, const int* in_sizes, int n_in,
                              void* d_out, int out_size, void* d_ws, size_t ws_size,
                              hipStream_t stream) {
    const float* x    = (const float*)d_in[0];
    const int*   eidx = (const int*)d_in[1];
    const float* W1   = (const float*)d_in[2];
    const float* b1   = (const float*)d_in[3];
    const float* W2   = (const float*)d_in[4];
    const float* b2   = (const float*)d_in[5];
    const float* Wmu  = (const float*)d_in[6];
    const float* bmu  = (const float*)d_in[7];
    const float* Wlv  = (const float*)d_in[8];
    const float* blv  = (const float*)d_in[9];
    float* out = (float*)d_out;

    const int* src = eidx;        // edge_index[0]
    const int* dst = eidx + NE;   // edge_index[1]

    // workspace layout (floats)
    float* ws   = (float*)d_ws;
    float* dinv = ws;                 // 50048
    float* en   = ws + 50048;         // 800000
    float* H    = ws + 850048;        // 6.4M
    float* AGG  = ws + 7250048;       // 6.4M

    const int gN  = (NN + 255) / 256;        // 196
    const int gE  = (NE + 255) / 256;        // 3125
    const int gEC = (NE * 32 + 255) / 256;   // 100000
    const int gNC = (NN * 32 + 255) / 256;   // 6250
    const int gG  = (NN + 31) / 32;          // 1563

    // gcn_norm
    k_init_deg<<<gN, 256, 0, stream>>>(dinv);
    k_count<<<gE, 256, 0, stream>>>(dst, dinv);
    k_dinv<<<gN, 256, 0, stream>>>(dinv);
    k_enorm<<<gE, 256, 0, stream>>>(src, dst, dinv, en);

    // conv1: H = x@W1; AGG = scatter; H = relu(AGG + H*sn + b1)
    k_gemm<<<gG, 256, 0, stream>>>(x, W1, H, NN);
    hipMemsetAsync(AGG, 0, (size_t)NN * 128 * sizeof(float), stream);
    k_scatter<<<gEC, 256, 0, stream>>>(H, en, src, dst, AGG);
    k_fuse<<<gNC, 256, 0, stream>>>(AGG, H, dinv, b1, H);

    // conv2: AGG = H@W2 (h2); H = scatter target; AGG = relu(H + AGG*sn + b2)
    k_gemm<<<gG, 256, 0, stream>>>(H, W2, AGG, NN);
    hipMemsetAsync(H, 0, (size_t)NN * 128 * sizeof(float), stream);
    k_scatter<<<gEC, 256, 0, stream>>>(AGG, en, src, dst, H);
    k_fuse<<<gNC, 256, 0, stream>>>(H, AGG, dinv, b2, AGG);

    // final projection
    k_final<<<gG, 256, 0, stream>>>(AGG, (const float4*)Wmu, bmu, (const float4*)Wlv, blv, out, NN);
}

// Round 2
// 530.568 us; speedup vs baseline: 5.7857x; 5.7857x over previous
//
#include <hip/hip_runtime.h>

#define NN 50000
#define NE 800000

// ================= CSR build =================
__global__ __launch_bounds__(256) void k_deg_init(int* deg) {
    int i = blockIdx.x * 256 + threadIdx.x;
    if (i < NN) deg[i] = 0;
}

__global__ __launch_bounds__(256) void k_deg_count(const int* __restrict__ dst, int* __restrict__ deg) {
    int e = blockIdx.x * 256 + threadIdx.x;
    if (e < NE) atomicAdd(&deg[dst[e]], 1);
}

__global__ __launch_bounds__(256) void k_dinv(const int* __restrict__ deg, float* __restrict__ dinv) {
    int i = blockIdx.x * 256 + threadIdx.x;
    if (i < NN) dinv[i] = rsqrtf((float)(deg[i] + 1));   // +1 = self loop
}

// scan pass 1: per-block sums of deg
__global__ __launch_bounds__(256) void k_scan1(const int* __restrict__ deg, int* __restrict__ bsum) {
    __shared__ int s[256];
    int tid = threadIdx.x;
    int i = blockIdx.x * 256 + tid;
    s[tid] = (i < NN) ? deg[i] : 0;
    __syncthreads();
    for (int d = 128; d > 0; d >>= 1) {
        if (tid < d) s[tid] += s[tid + d];
        __syncthreads();
    }
    if (tid == 0) bsum[blockIdx.x] = s[0];
}

// scan pass 2: exclusive scan of 196 block sums (single block)
__global__ __launch_bounds__(256) void k_scan2(int* bsum, int nblocks) {
    __shared__ int s[256];
    int tid = threadIdx.x;
    int v = (tid < nblocks) ? bsum[tid] : 0;
    s[tid] = v;
    __syncthreads();
    for (int d = 1; d < 256; d <<= 1) {
        int t = (tid >= d) ? s[tid - d] : 0;
        __syncthreads();
        s[tid] += t;
        __syncthreads();
    }
    if (tid < nblocks) bsum[tid] = s[tid] - v;   // exclusive
}

// scan pass 3: block-local exclusive scan + block offset -> off[]; copy into cursor (deg reused)
__global__ __launch_bounds__(256) void k_scan3(int* __restrict__ deg, const int* __restrict__ bsum,
                                               int* __restrict__ off) {
    __shared__ int s[256];
    int tid = threadIdx.x;
    int i = blockIdx.x * 256 + tid;
    int v = (i < NN) ? deg[i] : 0;
    s[tid] = v;
    __syncthreads();
    for (int d = 1; d < 256; d <<= 1) {
        int t = (tid >= d) ? s[tid - d] : 0;
        __syncthreads();
        s[tid] += t;
        __syncthreads();
    }
    int excl = bsum[blockIdx.x] + s[tid] - v;
    if (i < NN) { off[i] = excl; deg[i] = excl; }   // deg becomes cursor
    if (i == 0) off[NN] = NE;
}

// fill CSR: src_csr grouped by dst
__global__ __launch_bounds__(256) void k_fill(const int* __restrict__ src, const int* __restrict__ dst,
                                              int* __restrict__ cursor, int* __restrict__ src_csr) {
    int e = blockIdx.x * 256 + threadIdx.x;
    if (e >= NE) return;
    int d = dst[e];
    int p = atomicAdd(&cursor[d], 1);
    src_csr[p] = src[e];
}

// ================= dense GEMM: C[N,128] = X[N,128] @ W[128,128] =================
__global__ __launch_bounds__(256) void k_gemm(const float* __restrict__ X, const float* __restrict__ W,
                                              float* __restrict__ C, int N) {
    __shared__ float Ws[128 * 128];
    __shared__ float Xs[32 * 128];
    int tid  = threadIdx.x;
    int row0 = blockIdx.x * 32;

    const float4* W4 = (const float4*)W;
    float4* Ws4 = (float4*)Ws;
    for (int i = tid; i < 128 * 32; i += 256) Ws4[i] = W4[i];

    const float4* X4 = (const float4*)X;
    float4* Xs4 = (float4*)Xs;
    for (int i = tid; i < 32 * 32; i += 256) {
        int r = i >> 5, kk = i & 31;
        int gr = row0 + r;
        Xs4[i] = (gr < N) ? X4[gr * 32 + kk] : make_float4(0.f, 0.f, 0.f, 0.f);
    }
    __syncthreads();

    int c  = tid & 127;
    int rr = tid >> 7;
    float acc[16];
#pragma unroll
    for (int j = 0; j < 16; ++j) acc[j] = 0.f;

    for (int k = 0; k < 128; ++k) {
        float w = Ws[k * 128 + c];
#pragma unroll
        for (int j = 0; j < 16; ++j) acc[j] += Xs[(rr + 2 * j) * 128 + k] * w;
    }

#pragma unroll
    for (int j = 0; j < 16; ++j) {
        int r = row0 + rr + 2 * j;
        if (r < N) C[r * 128 + c] = acc[j];
    }
}

// ================= gather aggregation + self-loop + bias + relu =================
// one wave per dst node; lane handles 2 channels (float2). out must not alias h.
__global__ __launch_bounds__(256) void k_agg(const float* __restrict__ h, const int* __restrict__ off,
                                             const int* __restrict__ src_csr, const float* __restrict__ dinv,
                                             const float* __restrict__ b, float* __restrict__ out) {
    int lane = threadIdx.x & 63;
    int n = blockIdx.x * 4 + (threadIdx.x >> 6);   // grid = 12500 -> n < 50000 always
    int o0 = off[n], o1 = off[n + 1];
    float dn = dinv[n];
    const float2* h2 = (const float2*)h;

    float2 acc = {0.f, 0.f};
    int e = o0;
    for (; e + 1 < o1; e += 2) {
        int s0 = src_csr[e], s1 = src_csr[e + 1];
        float w0 = dinv[s0] * dn, w1 = dinv[s1] * dn;
        float2 v0 = h2[s0 * 64 + lane];
        float2 v1 = h2[s1 * 64 + lane];
        acc.x += v0.x * w0 + v1.x * w1;
        acc.y += v0.y * w0 + v1.y * w1;
    }
    if (e < o1) {
        int s0 = src_csr[e];
        float w0 = dinv[s0] * dn;
        float2 v0 = h2[s0 * 64 + lane];
        acc.x += v0.x * w0;
        acc.y += v0.y * w0;
    }

    float sn = dn * dn;
    float2 hv = h2[n * 64 + lane];
    float2 bb = ((const float2*)b)[lane];
    float2 r;
    r.x = fmaxf(acc.x + hv.x * sn + bb.x, 0.f);
    r.y = fmaxf(acc.y + hv.y * sn + bb.y, 0.f);
    ((float2*)out)[n * 64 + lane] = r;
}

// ================= final: mu = X@Wmu+bmu, lv = X@Wlv+blv, packed =================
__global__ __launch_bounds__(256) void k_final(const float* __restrict__ X,
                                               const float4* __restrict__ Wmu4, const float* __restrict__ bmu,
                                               const float4* __restrict__ Wlv4, const float* __restrict__ blv,
                                               float* __restrict__ out, int N) {
    __shared__ float Ws[128 * 128];
    __shared__ float Xs[32 * 128];
    __shared__ float Bs[128];
    int tid  = threadIdx.x;
    int row0 = blockIdx.x * 32;

    float4* Ws4 = (float4*)Ws;
    for (int i = tid; i < 2048; i += 256) {
        int k = i >> 4, c4 = i & 15;
        Ws4[k * 32 + c4]      = Wmu4[i];
        Ws4[k * 32 + 16 + c4] = Wlv4[i];
    }
    if (tid < 64) { Bs[tid] = bmu[tid]; Bs[64 + tid] = blv[tid]; }

    const float4* X4 = (const float4*)X;
    float4* Xs4 = (float4*)Xs;
    for (int i = tid; i < 32 * 32; i += 256) {
        int r = i >> 5, kk = i & 31;
        int gr = row0 + r;
        Xs4[i] = (gr < N) ? X4[gr * 32 + kk] : make_float4(0.f, 0.f, 0.f, 0.f);
    }
    __syncthreads();

    int c  = tid & 127;
    int rr = tid >> 7;
    float acc[16];
#pragma unroll
    for (int j = 0; j < 16; ++j) acc[j] = 0.f;

    for (int k = 0; k < 128; ++k) {
        float w = Ws[k * 128 + c];
#pragma unroll
        for (int j = 0; j < 16; ++j) acc[j] += Xs[(rr + 2 * j) * 128 + k] * w;
    }

    float bias = Bs[c];
#pragma unroll
    for (int j = 0; j < 16; ++j) {
        int r = row0 + rr + 2 * j;
        if (r < N) {
            if (c < 64) out[r * 64 + c] = acc[j] + bias;
            else        out[NN * 64 + r * 64 + (c - 64)] = acc[j] + bias;
        }
    }
}

extern "C" void kernel_launch(void* const* d_in, const int* in_sizes, int n_in,
                              void* d_out, int out_size, void* d_ws, size_t ws_size,
                              hipStream_t stream) {
    const float* x    = (const float*)d_in[0];
    const int*   eidx = (const int*)d_in[1];
    const float* W1   = (const float*)d_in[2];
    const float* b1   = (const float*)d_in[3];
    const float* W2   = (const float*)d_in[4];
    const float* b2   = (const float*)d_in[5];
    const float* Wmu  = (const float*)d_in[6];
    const float* bmu  = (const float*)d_in[7];
    const float* Wlv  = (const float*)d_in[8];
    const float* blv  = (const float*)d_in[9];
    float* out = (float*)d_out;

    const int* src = eidx;        // edge_index[0]
    const int* dst = eidx + NE;   // edge_index[1]

    // workspace layout (4-byte units)
    float* ws      = (float*)d_ws;
    float* dinv    = ws;                           // 50048
    int*   deg     = (int*)(ws + 50048);           // 50048 (becomes cursor)
    int*   off     = (int*)(ws + 100096);          // 50048 (N+1 used)
    int*   bsum    = (int*)(ws + 150144);          // 256
    int*   src_csr = (int*)(ws + 150400);          // 800000
    float* H       = ws + 950400;                  // 6.4M
    float* H2      = ws + 7350400;                 // 6.4M  (total ~55.0 MB)

    const int gN  = (NN + 255) / 256;   // 196
    const int gE  = (NE + 255) / 256;   // 3125
    const int gG  = (NN + 31) / 32;     // 1563
    const int gA  = NN / 4;             // 12500

    // ---- CSR build + norms ----
    k_deg_init<<<gN, 256, 0, stream>>>(deg);
    k_deg_count<<<gE, 256, 0, stream>>>(dst, deg);
    k_dinv<<<gN, 256, 0, stream>>>(deg, dinv);
    k_scan1<<<gN, 256, 0, stream>>>(deg, bsum);
    k_scan2<<<1, 256, 0, stream>>>(bsum, gN);
    k_scan3<<<gN, 256, 0, stream>>>(deg, bsum, off);
    k_fill<<<gE, 256, 0, stream>>>(src, dst, deg, src_csr);

    // ---- conv1: H = x@W1 ; H2 = relu(agg(H) + H*sn + b1) ----
    k_gemm<<<gG, 256, 0, stream>>>(x, W1, H, NN);
    k_agg<<<gA, 256, 0, stream>>>(H, off, src_csr, dinv, b1, H2);

    // ---- conv2: H = H2@W2 ; H2 = relu(agg(H) + H*sn + b2) ----
    k_gemm<<<gG, 256, 0, stream>>>(H2, W2, H, NN);
    k_agg<<<gA, 256, 0, stream>>>(H, off, src_csr, dinv, b2, H2);

    // ---- final projection ----
    k_final<<<gG, 256, 0, stream>>>(H2, (const float4*)Wmu, bmu, (const float4*)Wlv, blv, out, NN);
}

// Round 3
// 487.945 us; speedup vs baseline: 6.2910x; 1.0874x over previous
//
#include <hip/hip_runtime.h>

#define NN 50000
#define NE 800000

// ================= CSR build =================
__global__ __launch_bounds__(256) void k_deg_init(int* deg) {
    int i = blockIdx.x * 256 + threadIdx.x;
    if (i < NN) deg[i] = 0;
}

__global__ __launch_bounds__(256) void k_deg_count(const int* __restrict__ dst, int* __restrict__ deg) {
    int e = blockIdx.x * 256 + threadIdx.x;
    if (e < NE) atomicAdd(&deg[dst[e]], 1);
}

__global__ __launch_bounds__(256) void k_dinv(const int* __restrict__ deg, float* __restrict__ dinv) {
    int i = blockIdx.x * 256 + threadIdx.x;
    if (i < NN) dinv[i] = rsqrtf((float)(deg[i] + 1));   // +1 = self loop
}

__global__ __launch_bounds__(256) void k_scan1(const int* __restrict__ deg, int* __restrict__ bsum) {
    __shared__ int s[256];
    int tid = threadIdx.x;
    int i = blockIdx.x * 256 + tid;
    s[tid] = (i < NN) ? deg[i] : 0;
    __syncthreads();
    for (int d = 128; d > 0; d >>= 1) {
        if (tid < d) s[tid] += s[tid + d];
        __syncthreads();
    }
    if (tid == 0) bsum[blockIdx.x] = s[0];
}

__global__ __launch_bounds__(256) void k_scan2(int* bsum, int nblocks) {
    __shared__ int s[256];
    int tid = threadIdx.x;
    int v = (tid < nblocks) ? bsum[tid] : 0;
    s[tid] = v;
    __syncthreads();
    for (int d = 1; d < 256; d <<= 1) {
        int t = (tid >= d) ? s[tid - d] : 0;
        __syncthreads();
        s[tid] += t;
        __syncthreads();
    }
    if (tid < nblocks) bsum[tid] = s[tid] - v;   // exclusive
}

__global__ __launch_bounds__(256) void k_scan3(int* __restrict__ deg, const int* __restrict__ bsum,
                                               int* __restrict__ off) {
    __shared__ int s[256];
    int tid = threadIdx.x;
    int i = blockIdx.x * 256 + tid;
    int v = (i < NN) ? deg[i] : 0;
    s[tid] = v;
    __syncthreads();
    for (int d = 1; d < 256; d <<= 1) {
        int t = (tid >= d) ? s[tid - d] : 0;
        __syncthreads();
        s[tid] += t;
        __syncthreads();
    }
    int excl = bsum[blockIdx.x] + s[tid] - v;
    if (i < NN) { off[i] = excl; deg[i] = excl; }   // deg becomes cursor
    if (i == 0) off[NN] = NE;
}

__global__ __launch_bounds__(256) void k_fill(const int* __restrict__ src, const int* __restrict__ dst,
                                              int* __restrict__ cursor, int* __restrict__ src_csr) {
    int e = blockIdx.x * 256 + threadIdx.x;
    if (e >= NE) return;
    int d = dst[e];
    int p = atomicAdd(&cursor[d], 1);
    src_csr[p] = src[e];
}

// ================= GEMM: C[N,128] = X[N,128] @ W[128,128] =================
// 256 thr, 64-row tile; thread = 8 rows x 4 cols; Xs transposed [k][row]; dbuf LDS 48KB.
__global__ __launch_bounds__(256, 3) void k_gemm(const float* __restrict__ X,
                                                 const float* __restrict__ W,
                                                 float* __restrict__ C, int N) {
    __shared__ float Xs[2][32][64];
    __shared__ float Ws[2][32][128];
    int tid  = threadIdx.x;
    int row0 = blockIdx.x * 64;
    int tc = tid & 31, tr = tid >> 5;

    const float4* X4 = (const float4*)X;
    const float4* W4 = (const float4*)W;

    float acc[8][4];
#pragma unroll
    for (int i = 0; i < 8; ++i)
#pragma unroll
        for (int j = 0; j < 4; ++j) acc[i][j] = 0.f;

#define STAGE(kk, buf)                                                        \
    {                                                                         \
        _Pragma("unroll")                                                     \
        for (int i = 0; i < 2; ++i) {                                         \
            int idx = tid + i * 256;                                          \
            int r = idx >> 3, q = idx & 7;                                    \
            int gr = row0 + r;                                                \
            float4 v = (gr < N) ? X4[gr * 32 + (kk) * 8 + q]                  \
                                : make_float4(0.f, 0.f, 0.f, 0.f);            \
            Xs[buf][q * 4 + 0][r] = v.x;                                      \
            Xs[buf][q * 4 + 1][r] = v.y;                                      \
            Xs[buf][q * 4 + 2][r] = v.z;                                      \
            Xs[buf][q * 4 + 3][r] = v.w;                                      \
        }                                                                     \
        _Pragma("unroll")                                                     \
        for (int i = 0; i < 4; ++i) {                                         \
            int idx = tid + i * 256;                                          \
            int k = idx >> 5, cq = idx & 31;                                  \
            float4 v = W4[((kk) * 32 + k) * 32 + cq];                         \
            *(float4*)&Ws[buf][k][cq * 4] = v;                                \
        }                                                                     \
    }

    STAGE(0, 0);
    for (int kk = 0; kk < 4; ++kk) {
        __syncthreads();
        if (kk < 3) STAGE(kk + 1, (kk + 1) & 1);
        int buf = kk & 1;
#pragma unroll 8
        for (int k = 0; k < 32; ++k) {
            float4 xa = *(const float4*)&Xs[buf][k][tr * 8];
            float4 xb = *(const float4*)&Xs[buf][k][tr * 8 + 4];
            float4 wv = *(const float4*)&Ws[buf][k][tc * 4];
            float xr[8] = {xa.x, xa.y, xa.z, xa.w, xb.x, xb.y, xb.z, xb.w};
            float wr[4] = {wv.x, wv.y, wv.z, wv.w};
#pragma unroll
            for (int i = 0; i < 8; ++i)
#pragma unroll
                for (int j = 0; j < 4; ++j) acc[i][j] += xr[i] * wr[j];
        }
    }
#undef STAGE

#pragma unroll
    for (int i = 0; i < 8; ++i) {
        int r = row0 + tr * 8 + i;
        if (r < N) {
            float4 v = make_float4(acc[i][0], acc[i][1], acc[i][2], acc[i][3]);
            *(float4*)&C[r * 128 + tc * 4] = v;
        }
    }
}

// ================= final: [mu | lv] = X @ [Wmu|Wlv] + [bmu|blv], packed out =================
__global__ __launch_bounds__(256, 3) void k_final(const float* __restrict__ X,
                                                  const float4* __restrict__ Wmu4, const float* __restrict__ bmu,
                                                  const float4* __restrict__ Wlv4, const float* __restrict__ blv,
                                                  float* __restrict__ out, int N) {
    __shared__ float Xs[2][32][64];
    __shared__ float Ws[2][32][128];
    int tid  = threadIdx.x;
    int row0 = blockIdx.x * 64;
    int tc = tid & 31, tr = tid >> 5;

    const float4* X4 = (const float4*)X;

    float acc[8][4];
#pragma unroll
    for (int i = 0; i < 8; ++i)
#pragma unroll
        for (int j = 0; j < 4; ++j) acc[i][j] = 0.f;

#define STAGEF(kk, buf)                                                       \
    {                                                                         \
        _Pragma("unroll")                                                     \
        for (int i = 0; i < 2; ++i) {                                         \
            int idx = tid + i * 256;                                          \
            int r = idx >> 3, q = idx & 7;                                    \
            int gr = row0 + r;                                                \
            float4 v = (gr < N) ? X4[gr * 32 + (kk) * 8 + q]                  \
                                : make_float4(0.f, 0.f, 0.f, 0.f);            \
            Xs[buf][q * 4 + 0][r] = v.x;                                      \
            Xs[buf][q * 4 + 1][r] = v.y;                                      \
            Xs[buf][q * 4 + 2][r] = v.z;                                      \
            Xs[buf][q * 4 + 3][r] = v.w;                                      \
        }                                                                     \
        _Pragma("unroll")                                                     \
        for (int i = 0; i < 4; ++i) {                                         \
            int idx = tid + i * 256;                                          \
            int k = idx >> 5, cq = idx & 31;                                  \
            float4 v = (cq < 16) ? Wmu4[((kk) * 32 + k) * 16 + cq]            \
                                 : Wlv4[((kk) * 32 + k) * 16 + (cq - 16)];    \
            *(float4*)&Ws[buf][k][cq * 4] = v;                                \
        }                                                                     \
    }

    STAGEF(0, 0);
    for (int kk = 0; kk < 4; ++kk) {
        __syncthreads();
        if (kk < 3) STAGEF(kk + 1, (kk + 1) & 1);
        int buf = kk & 1;
#pragma unroll 8
        for (int k = 0; k < 32; ++k) {
            float4 xa = *(const float4*)&Xs[buf][k][tr * 8];
            float4 xb = *(const float4*)&Xs[buf][k][tr * 8 + 4];
            float4 wv = *(const float4*)&Ws[buf][k][tc * 4];
            float xr[8] = {xa.x, xa.y, xa.z, xa.w, xb.x, xb.y, xb.z, xb.w};
            float wr[4] = {wv.x, wv.y, wv.z, wv.w};
#pragma unroll
            for (int i = 0; i < 8; ++i)
#pragma unroll
                for (int j = 0; j < 4; ++j) acc[i][j] += xr[i] * wr[j];
        }
    }
#undef STAGEF

    float4 bb = (tc < 16) ? *(const float4*)&bmu[tc * 4]
                          : *(const float4*)&blv[tc * 4 - 64];
#pragma unroll
    for (int i = 0; i < 8; ++i) {
        int r = row0 + tr * 8 + i;
        if (r < N) {
            float4 v = make_float4(acc[i][0] + bb.x, acc[i][1] + bb.y,
                                   acc[i][2] + bb.z, acc[i][3] + bb.w);
            if (tc < 16) *(float4*)&out[r * 64 + tc * 4] = v;
            else         *(float4*)&out[(size_t)NN * 64 + r * 64 + tc * 4 - 64] = v;
        }
    }
}

// ================= gather agg + self-loop + bias + relu, channel-chunked =================
// chunk = blockIdx&7 rides the round-robin block->XCD mapping: each XCD gathers a
// 16-channel (3.2MB) column slice of h -> L2-resident. 8 lanes/node (float2 x8 = 16ch),
// 32 nodes/block.
__global__ __launch_bounds__(256) void k_agg(const float* __restrict__ h, const int* __restrict__ off,
                                             const int* __restrict__ src_csr, const float* __restrict__ dinv,
                                             const float* __restrict__ b, float* __restrict__ out) {
    int chunk = blockIdx.x & 7;
    int g     = blockIdx.x >> 3;
    int sub   = threadIdx.x & 7;
    int n     = g * 32 + (threadIdx.x >> 3);
    if (n >= NN) return;
    int o0 = off[n], o1 = off[n + 1];
    float dn = dinv[n];
    const float2* h2 = (const float2*)h;
    int cb = chunk * 8 + sub;   // float2 index within the 64-float2 row

    float2 acc = {0.f, 0.f};
    int e = o0;
    for (; e + 1 < o1; e += 2) {
        int s0 = src_csr[e], s1 = src_csr[e + 1];
        float w0 = dinv[s0] * dn, w1 = dinv[s1] * dn;
        float2 v0 = h2[s0 * 64 + cb];
        float2 v1 = h2[s1 * 64 + cb];
        acc.x += v0.x * w0 + v1.x * w1;
        acc.y += v0.y * w0 + v1.y * w1;
    }
    if (e < o1) {
        int s0 = src_csr[e];
        float w0 = dinv[s0] * dn;
        float2 v0 = h2[s0 * 64 + cb];
        acc.x += v0.x * w0;
        acc.y += v0.y * w0;
    }

    float sn = dn * dn;
    float2 hv = h2[n * 64 + cb];
    float2 bb = ((const float2*)b)[cb];
    float2 r;
    r.x = fmaxf(acc.x + hv.x * sn + bb.x, 0.f);
    r.y = fmaxf(acc.y + hv.y * sn + bb.y, 0.f);
    ((float2*)out)[n * 64 + cb] = r;
}

extern "C" void kernel_launch(void* const* d_in, const int* in_sizes, int n_in,
                              void* d_out, int out_size, void* d_ws, size_t ws_size,
                              hipStream_t stream) {
    const float* x    = (const float*)d_in[0];
    const int*   eidx = (const int*)d_in[1];
    const float* W1   = (const float*)d_in[2];
    const float* b1   = (const float*)d_in[3];
    const float* W2   = (const float*)d_in[4];
    const float* b2   = (const float*)d_in[5];
    const float* Wmu  = (const float*)d_in[6];
    const float* bmu  = (const float*)d_in[7];
    const float* Wlv  = (const float*)d_in[8];
    const float* blv  = (const float*)d_in[9];
    float* out = (float*)d_out;

    const int* src = eidx;        // edge_index[0]
    const int* dst = eidx + NE;   // edge_index[1]

    // workspace layout (4-byte units)
    float* ws      = (float*)d_ws;
    float* dinv    = ws;                           // 50048
    int*   deg     = (int*)(ws + 50048);           // 50048 (becomes cursor)
    int*   off     = (int*)(ws + 100096);          // 50048 (N+1 used)
    int*   bsum    = (int*)(ws + 150144);          // 256
    int*   src_csr = (int*)(ws + 150400);          // 800000
    float* H       = ws + 950400;                  // 6.4M
    float* H2      = ws + 7350400;                 // 6.4M

    const int gN  = (NN + 255) / 256;   // 196
    const int gE  = (NE + 255) / 256;   // 3125
    const int gG  = (NN + 63) / 64;     // 782
    const int gA  = ((NN + 31) / 32) * 8;  // 12504

    // ---- CSR build + norms ----
    k_deg_init<<<gN, 256, 0, stream>>>(deg);
    k_deg_count<<<gE, 256, 0, stream>>>(dst, deg);
    k_dinv<<<gN, 256, 0, stream>>>(deg, dinv);
    k_scan1<<<gN, 256, 0, stream>>>(deg, bsum);
    k_scan2<<<1, 256, 0, stream>>>(bsum, gN);
    k_scan3<<<gN, 256, 0, stream>>>(deg, bsum, off);
    k_fill<<<gE, 256, 0, stream>>>(src, dst, deg, src_csr);

    // ---- conv1 ----
    k_gemm<<<gG, 256, 0, stream>>>(x, W1, H, NN);
    k_agg<<<gA, 256, 0, stream>>>(H, off, src_csr, dinv, b1, H2);

    // ---- conv2 ----
    k_gemm<<<gG, 256, 0, stream>>>(H2, W2, H, NN);
    k_agg<<<gA, 256, 0, stream>>>(H, off, src_csr, dinv, b2, H2);

    // ---- final projection ----
    k_final<<<gG, 256, 0, stream>>>(H2, (const float4*)Wmu, bmu, (const float4*)Wlv, blv, out, NN);
}

// Round 4
// 434.787 us; speedup vs baseline: 7.0602x; 1.1223x over previous
//
#include <hip/hip_runtime.h>

#define NN 50000
#define NE 800000

// ================= CSR build =================
__global__ __launch_bounds__(256) void k_deg_init(int* deg) {
    int i = blockIdx.x * 256 + threadIdx.x;
    if (i < NN) deg[i] = 0;
}

__global__ __launch_bounds__(256) void k_deg_count(const int* __restrict__ dst, int* __restrict__ deg) {
    int e = blockIdx.x * 256 + threadIdx.x;
    if (e < NE) atomicAdd(&deg[dst[e]], 1);
}

__global__ __launch_bounds__(256) void k_dinv(const int* __restrict__ deg, float* __restrict__ dinv) {
    int i = blockIdx.x * 256 + threadIdx.x;
    if (i < NN) dinv[i] = rsqrtf((float)(deg[i] + 1));   // +1 = self loop
}

__global__ __launch_bounds__(256) void k_scan1(const int* __restrict__ deg, int* __restrict__ bsum) {
    __shared__ int s[256];
    int tid = threadIdx.x;
    int i = blockIdx.x * 256 + tid;
    s[tid] = (i < NN) ? deg[i] : 0;
    __syncthreads();
    for (int d = 128; d > 0; d >>= 1) {
        if (tid < d) s[tid] += s[tid + d];
        __syncthreads();
    }
    if (tid == 0) bsum[blockIdx.x] = s[0];
}

__global__ __launch_bounds__(256) void k_scan2(int* bsum, int nblocks) {
    __shared__ int s[256];
    int tid = threadIdx.x;
    int v = (tid < nblocks) ? bsum[tid] : 0;
    s[tid] = v;
    __syncthreads();
    for (int d = 1; d < 256; d <<= 1) {
        int t = (tid >= d) ? s[tid - d] : 0;
        __syncthreads();
        s[tid] += t;
        __syncthreads();
    }
    if (tid < nblocks) bsum[tid] = s[tid] - v;   // exclusive
}

__global__ __launch_bounds__(256) void k_scan3(int* __restrict__ deg, const int* __restrict__ bsum,
                                               int* __restrict__ off) {
    __shared__ int s[256];
    int tid = threadIdx.x;
    int i = blockIdx.x * 256 + tid;
    int v = (i < NN) ? deg[i] : 0;
    s[tid] = v;
    __syncthreads();
    for (int d = 1; d < 256; d <<= 1) {
        int t = (tid >= d) ? s[tid - d] : 0;
        __syncthreads();
        s[tid] += t;
        __syncthreads();
    }
    int excl = bsum[blockIdx.x] + s[tid] - v;
    if (i < NN) { off[i] = excl; deg[i] = excl; }   // deg becomes cursor
    if (i == 0) off[NN] = NE;
}

// fill CSR with (src, weight) pairs; weight = dinv[src]*dinv[dst] precomputed
__global__ __launch_bounds__(256) void k_fill(const int* __restrict__ src, const int* __restrict__ dst,
                                              const float* __restrict__ dinv,
                                              int* __restrict__ cursor, int2* __restrict__ epair) {
    int e = blockIdx.x * 256 + threadIdx.x;
    if (e >= NE) return;
    int s = src[e], d = dst[e];
    int p = atomicAdd(&cursor[d], 1);
    epair[p] = make_int2(s, __float_as_int(dinv[s] * dinv[d]));
}

// ================= GEMM: C[N,128] = X[N,128] @ W[128,128] =================
__global__ __launch_bounds__(256, 3) void k_gemm(const float* __restrict__ X,
                                                 const float* __restrict__ W,
                                                 float* __restrict__ C, int N) {
    __shared__ float Xs[2][32][64];
    __shared__ float Ws[2][32][128];
    int tid  = threadIdx.x;
    int row0 = blockIdx.x * 64;
    int tc = tid & 31, tr = tid >> 5;

    const float4* X4 = (const float4*)X;
    const float4* W4 = (const float4*)W;

    float acc[8][4];
#pragma unroll
    for (int i = 0; i < 8; ++i)
#pragma unroll
        for (int j = 0; j < 4; ++j) acc[i][j] = 0.f;

#define STAGE(kk, buf)                                                        \
    {                                                                         \
        _Pragma("unroll")                                                     \
        for (int i = 0; i < 2; ++i) {                                         \
            int idx = tid + i * 256;                                          \
            int r = idx >> 3, q = idx & 7;                                    \
            int gr = row0 + r;                                                \
            float4 v = (gr < N) ? X4[gr * 32 + (kk) * 8 + q]                  \
                                : make_float4(0.f, 0.f, 0.f, 0.f);            \
            Xs[buf][q * 4 + 0][r] = v.x;                                      \
            Xs[buf][q * 4 + 1][r] = v.y;                                      \
            Xs[buf][q * 4 + 2][r] = v.z;                                      \
            Xs[buf][q * 4 + 3][r] = v.w;                                      \
        }                                                                     \
        _Pragma("unroll")                                                     \
        for (int i = 0; i < 4; ++i) {                                         \
            int idx = tid + i * 256;                                          \
            int k = idx >> 5, cq = idx & 31;                                  \
            float4 v = W4[((kk) * 32 + k) * 32 + cq];                         \
            *(float4*)&Ws[buf][k][cq * 4] = v;                                \
        }                                                                     \
    }

    STAGE(0, 0);
    for (int kk = 0; kk < 4; ++kk) {
        __syncthreads();
        if (kk < 3) STAGE(kk + 1, (kk + 1) & 1);
        int buf = kk & 1;
#pragma unroll 8
        for (int k = 0; k < 32; ++k) {
            float4 xa = *(const float4*)&Xs[buf][k][tr * 8];
            float4 xb = *(const float4*)&Xs[buf][k][tr * 8 + 4];
            float4 wv = *(const float4*)&Ws[buf][k][tc * 4];
            float xr[8] = {xa.x, xa.y, xa.z, xa.w, xb.x, xb.y, xb.z, xb.w};
            float wr[4] = {wv.x, wv.y, wv.z, wv.w};
#pragma unroll
            for (int i = 0; i < 8; ++i)
#pragma unroll
                for (int j = 0; j < 4; ++j) acc[i][j] += xr[i] * wr[j];
        }
    }
#undef STAGE

#pragma unroll
    for (int i = 0; i < 8; ++i) {
        int r = row0 + tr * 8 + i;
        if (r < N) {
            float4 v = make_float4(acc[i][0], acc[i][1], acc[i][2], acc[i][3]);
            *(float4*)&C[r * 128 + tc * 4] = v;
        }
    }
}

// ================= final: [mu | lv] = X @ [Wmu|Wlv] + [bmu|blv], packed out =================
__global__ __launch_bounds__(256, 3) void k_final(const float* __restrict__ X,
                                                  const float4* __restrict__ Wmu4, const float* __restrict__ bmu,
                                                  const float4* __restrict__ Wlv4, const float* __restrict__ blv,
                                                  float* __restrict__ out, int N) {
    __shared__ float Xs[2][32][64];
    __shared__ float Ws[2][32][128];
    int tid  = threadIdx.x;
    int row0 = blockIdx.x * 64;
    int tc = tid & 31, tr = tid >> 5;

    const float4* X4 = (const float4*)X;

    float acc[8][4];
#pragma unroll
    for (int i = 0; i < 8; ++i)
#pragma unroll
        for (int j = 0; j < 4; ++j) acc[i][j] = 0.f;

#define STAGEF(kk, buf)                                                       \
    {                                                                         \
        _Pragma("unroll")                                                     \
        for (int i = 0; i < 2; ++i) {                                         \
            int idx = tid + i * 256;                                          \
            int r = idx >> 3, q = idx & 7;                                    \
            int gr = row0 + r;                                                \
            float4 v = (gr < N) ? X4[gr * 32 + (kk) * 8 + q]                  \
                                : make_float4(0.f, 0.f, 0.f, 0.f);            \
            Xs[buf][q * 4 + 0][r] = v.x;                                      \
            Xs[buf][q * 4 + 1][r] = v.y;                                      \
            Xs[buf][q * 4 + 2][r] = v.z;                                      \
            Xs[buf][q * 4 + 3][r] = v.w;                                      \
        }                                                                     \
        _Pragma("unroll")                                                     \
        for (int i = 0; i < 4; ++i) {                                         \
            int idx = tid + i * 256;                                          \
            int k = idx >> 5, cq = idx & 31;                                  \
            float4 v = (cq < 16) ? Wmu4[((kk) * 32 + k) * 16 + cq]            \
                                 : Wlv4[((kk) * 32 + k) * 16 + (cq - 16)];    \
            *(float4*)&Ws[buf][k][cq * 4] = v;                                \
        }                                                                     \
    }

    STAGEF(0, 0);
    for (int kk = 0; kk < 4; ++kk) {
        __syncthreads();
        if (kk < 3) STAGEF(kk + 1, (kk + 1) & 1);
        int buf = kk & 1;
#pragma unroll 8
        for (int k = 0; k < 32; ++k) {
            float4 xa = *(const float4*)&Xs[buf][k][tr * 8];
            float4 xb = *(const float4*)&Xs[buf][k][tr * 8 + 4];
            float4 wv = *(const float4*)&Ws[buf][k][tc * 4];
            float xr[8] = {xa.x, xa.y, xa.z, xa.w, xb.x, xb.y, xb.z, xb.w};
            float wr[4] = {wv.x, wv.y, wv.z, wv.w};
#pragma unroll
            for (int i = 0; i < 8; ++i)
#pragma unroll
                for (int j = 0; j < 4; ++j) acc[i][j] += xr[i] * wr[j];
        }
    }
#undef STAGEF

    float4 bb = (tc < 16) ? *(const float4*)&bmu[tc * 4]
                          : *(const float4*)&blv[tc * 4 - 64];
#pragma unroll
    for (int i = 0; i < 8; ++i) {
        int r = row0 + tr * 8 + i;
        if (r < N) {
            float4 v = make_float4(acc[i][0] + bb.x, acc[i][1] + bb.y,
                                   acc[i][2] + bb.z, acc[i][3] + bb.w);
            if (tc < 16) *(float4*)&out[r * 64 + tc * 4] = v;
            else         *(float4*)&out[(size_t)NN * 64 + r * 64 + tc * 4 - 64] = v;
        }
    }
}

// ================= gather agg + self-loop + bias + relu =================
// 8 lanes/node (16 ch via float2), 32 nodes/block, chunk = blockIdx&7 (XCD slice).
// 8-deep edge unroll: 8 independent gathers in flight per wave per round.
__global__ __launch_bounds__(256) void k_agg(const float* __restrict__ h, const int* __restrict__ off,
                                             const int2* __restrict__ epair, const float* __restrict__ dinv,
                                             const float* __restrict__ b, float* __restrict__ out) {
    int chunk = blockIdx.x & 7;
    int g     = blockIdx.x >> 3;
    int sub   = threadIdx.x & 7;
    int n     = g * 32 + (threadIdx.x >> 3);
    if (n >= NN) return;
    int o0 = off[n], o1 = off[n + 1];
    const float2* h2 = (const float2*)h;
    int cb = chunk * 8 + sub;   // float2 index within the 64-float2 row

    float2 a0 = {0.f, 0.f}, a1 = {0.f, 0.f}, a2 = {0.f, 0.f}, a3 = {0.f, 0.f};
    int e = o0;
    for (; e + 8 <= o1; e += 8) {
        int2 p0 = epair[e + 0], p1 = epair[e + 1], p2 = epair[e + 2], p3 = epair[e + 3];
        int2 p4 = epair[e + 4], p5 = epair[e + 5], p6 = epair[e + 6], p7 = epair[e + 7];
        float2 v0 = h2[p0.x * 64 + cb];
        float2 v1 = h2[p1.x * 64 + cb];
        float2 v2 = h2[p2.x * 64 + cb];
        float2 v3 = h2[p3.x * 64 + cb];
        float2 v4 = h2[p4.x * 64 + cb];
        float2 v5 = h2[p5.x * 64 + cb];
        float2 v6 = h2[p6.x * 64 + cb];
        float2 v7 = h2[p7.x * 64 + cb];
        float w0 = __int_as_float(p0.y), w1 = __int_as_float(p1.y);
        float w2 = __int_as_float(p2.y), w3 = __int_as_float(p3.y);
        float w4 = __int_as_float(p4.y), w5 = __int_as_float(p5.y);
        float w6 = __int_as_float(p6.y), w7 = __int_as_float(p7.y);
        a0.x += v0.x * w0; a0.y += v0.y * w0;
        a1.x += v1.x * w1; a1.y += v1.y * w1;
        a2.x += v2.x * w2; a2.y += v2.y * w2;
        a3.x += v3.x * w3; a3.y += v3.y * w3;
        a0.x += v4.x * w4; a0.y += v4.y * w4;
        a1.x += v5.x * w5; a1.y += v5.y * w5;
        a2.x += v6.x * w6; a2.y += v6.y * w6;
        a3.x += v7.x * w7; a3.y += v7.y * w7;
    }
    if (e + 4 <= o1) {
        int2 p0 = epair[e + 0], p1 = epair[e + 1], p2 = epair[e + 2], p3 = epair[e + 3];
        float2 v0 = h2[p0.x * 64 + cb];
        float2 v1 = h2[p1.x * 64 + cb];
        float2 v2 = h2[p2.x * 64 + cb];
        float2 v3 = h2[p3.x * 64 + cb];
        float w0 = __int_as_float(p0.y), w1 = __int_as_float(p1.y);
        float w2 = __int_as_float(p2.y), w3 = __int_as_float(p3.y);
        a0.x += v0.x * w0; a0.y += v0.y * w0;
        a1.x += v1.x * w1; a1.y += v1.y * w1;
        a2.x += v2.x * w2; a2.y += v2.y * w2;
        a3.x += v3.x * w3; a3.y += v3.y * w3;
        e += 4;
    }
    for (; e < o1; ++e) {
        int2 p = epair[e];
        float2 v = h2[p.x * 64 + cb];
        float w = __int_as_float(p.y);
        a0.x += v.x * w; a0.y += v.y * w;
    }

    float dn = dinv[n];
    float sn = dn * dn;
    float2 hv = h2[n * 64 + cb];
    float2 bb = ((const float2*)b)[cb];
    float2 r;
    r.x = fmaxf((a0.x + a1.x) + (a2.x + a3.x) + hv.x * sn + bb.x, 0.f);
    r.y = fmaxf((a0.y + a1.y) + (a2.y + a3.y) + hv.y * sn + bb.y, 0.f);
    ((float2*)out)[n * 64 + cb] = r;
}

extern "C" void kernel_launch(void* const* d_in, const int* in_sizes, int n_in,
                              void* d_out, int out_size, void* d_ws, size_t ws_size,
                              hipStream_t stream) {
    const float* x    = (const float*)d_in[0];
    const int*   eidx = (const int*)d_in[1];
    const float* W1   = (const float*)d_in[2];
    const float* b1   = (const float*)d_in[3];
    const float* W2   = (const float*)d_in[4];
    const float* b2   = (const float*)d_in[5];
    const float* Wmu  = (const float*)d_in[6];
    const float* bmu  = (const float*)d_in[7];
    const float* Wlv  = (const float*)d_in[8];
    const float* blv  = (const float*)d_in[9];
    float* out = (float*)d_out;

    const int* src = eidx;        // edge_index[0]
    const int* dst = eidx + NE;   // edge_index[1]

    // workspace layout (4-byte units)
    float* ws      = (float*)d_ws;
    float* dinv    = ws;                           // 50048
    int*   deg     = (int*)(ws + 50048);           // 50048 (becomes cursor)
    int*   off     = (int*)(ws + 100096);          // 50048 (N+1 used)
    int*   bsum    = (int*)(ws + 150144);          // 256
    int2*  epair   = (int2*)(ws + 150400);         // 800000 int2 (8B-aligned)
    float* H       = ws + 1750400;                 // 6.4M
    float* H2      = ws + 8150400;                 // 6.4M  (total ~58.2 MB)

    const int gN  = (NN + 255) / 256;      // 196
    const int gE  = (NE + 255) / 256;      // 3125
    const int gG  = (NN + 63) / 64;        // 782
    const int gA  = ((NN + 31) / 32) * 8;  // 12504

    // ---- CSR build + norms ----
    k_deg_init<<<gN, 256, 0, stream>>>(deg);
    k_deg_count<<<gE, 256, 0, stream>>>(dst, deg);
    k_dinv<<<gN, 256, 0, stream>>>(deg, dinv);
    k_scan1<<<gN, 256, 0, stream>>>(deg, bsum);
    k_scan2<<<1, 256, 0, stream>>>(bsum, gN);
    k_scan3<<<gN, 256, 0, stream>>>(deg, bsum, off);
    k_fill<<<gE, 256, 0, stream>>>(src, dst, dinv, deg, epair);

    // ---- conv1 ----
    k_gemm<<<gG, 256, 0, stream>>>(x, W1, H, NN);
    k_agg<<<gA, 256, 0, stream>>>(H, off, epair, dinv, b1, H2);

    // ---- conv2 ----
    k_gemm<<<gG, 256, 0, stream>>>(H2, W2, H, NN);
    k_agg<<<gA, 256, 0, stream>>>(H, off, epair, dinv, b2, H2);

    // ---- final projection ----
    k_final<<<gG, 256, 0, stream>>>(H2, (const float4*)Wmu, bmu, (const float4*)Wlv, blv, out, NN);
}